// Round 1
// baseline (1059.869 us; speedup 1.0000x reference)
//
#include <hip/hip_runtime.h>
#include <stdint.h>
#include <stddef.h>

#define TSTEPS 2048
#define BATCH  512
#define IDIM   28
#define NDIM   256

typedef __attribute__((ext_vector_type(4))) float f32x4;
typedef __attribute__((ext_vector_type(8))) short short8;

#define MFMA __builtin_amdgcn_mfma_f32_16x16x32_bf16

// pack two f32x4 into 8 bf16 (RNE) slots: v[0..3]=a, v[4..7]=b
__device__ __forceinline__ short8 pack2(f32x4 a, f32x4 b) {
  union { uint32_t u[4]; short8 s; } r;
  asm("v_cvt_pk_bf16_f32 %0, %1, %2" : "=v"(r.u[0]) : "v"(a[0]), "v"(a[1]));
  asm("v_cvt_pk_bf16_f32 %0, %1, %2" : "=v"(r.u[1]) : "v"(a[2]), "v"(a[3]));
  asm("v_cvt_pk_bf16_f32 %0, %1, %2" : "=v"(r.u[2]) : "v"(b[0]), "v"(b[1]));
  asm("v_cvt_pk_bf16_f32 %0, %1, %2" : "=v"(r.u[3]) : "v"(b[2]), "v"(b[3]));
  return r.s;
}

// One timestep. P = LDS buffer parity (== t&1). DLO/DHI hold data[t] (f32),
// and get re-loaded with data[t+2] (distance-2 register prefetch).
#define RNN_STEP(P, DLO, DHI, tcur)                                           \
  {                                                                           \
    short8 Bx = pack2(DLO, DHI);                                              \
    {                                                                         \
      int tt = (tcur) + 2; tt = (tt > TSTEPS - 1) ? (TSTEPS - 1) : tt;        \
      const float* rp = dptr + (size_t)tt * (BATCH * IDIM);                   \
      DLO = *(const f32x4*)rp;                                                \
      if (g < 3) DHI = *(const f32x4*)(rp + 16);                              \
    }                                                                         \
    const short8* rb = (const short8*)(&ldsf[(P)][0][0][0]);                  \
    short8 B0 = rb[0 * 64 + lane], B1 = rb[1 * 64 + lane];                    \
    short8 B2 = rb[2 * 64 + lane], B3 = rb[3 * 64 + lane];                    \
    short8 B4 = rb[4 * 64 + lane], B5 = rb[5 * 64 + lane];                    \
    short8 B6 = rb[6 * 64 + lane], B7 = rb[7 * 64 + lane];                    \
    f32x4 acc0, acc1;                                                         \
    _Pragma("unroll")                                                         \
    for (int r = 0; r < 4; ++r) {                                             \
      acc0[r] = __builtin_fmaf(0.5f, h0r[r], cst0[r]);                        \
      acc1[r] = __builtin_fmaf(0.5f, h1r[r], cst1[r]);                        \
    }                                                                         \
    acc0 = MFMA(A_hh0[0], B0, acc0, 0, 0, 0);                                 \
    acc1 = MFMA(A_hh1[0], B0, acc1, 0, 0, 0);                                 \
    acc0 = MFMA(A_hh0[1], B1, acc0, 0, 0, 0);                                 \
    acc1 = MFMA(A_hh1[1], B1, acc1, 0, 0, 0);                                 \
    acc0 = MFMA(A_hh0[2], B2, acc0, 0, 0, 0);                                 \
    acc1 = MFMA(A_hh1[2], B2, acc1, 0, 0, 0);                                 \
    acc0 = MFMA(A_hh0[3], B3, acc0, 0, 0, 0);                                 \
    acc1 = MFMA(A_hh1[3], B3, acc1, 0, 0, 0);                                 \
    acc0 = MFMA(A_hh0[4], B4, acc0, 0, 0, 0);                                 \
    acc1 = MFMA(A_hh1[4], B4, acc1, 0, 0, 0);                                 \
    acc0 = MFMA(A_hh0[5], B5, acc0, 0, 0, 0);                                 \
    acc1 = MFMA(A_hh1[5], B5, acc1, 0, 0, 0);                                 \
    acc0 = MFMA(A_hh0[6], B6, acc0, 0, 0, 0);                                 \
    acc1 = MFMA(A_hh1[6], B6, acc1, 0, 0, 0);                                 \
    acc0 = MFMA(A_hh0[7], B7, acc0, 0, 0, 0);                                 \
    acc1 = MFMA(A_hh1[7], B7, acc1, 0, 0, 0);                                 \
    acc0 = MFMA(A_in0, Bx, acc0, 0, 0, 0);                                    \
    acc1 = MFMA(A_in1, Bx, acc1, 0, 0, 0);                                    \
    _Pragma("unroll")                                                         \
    for (int r = 0; r < 4; ++r) {                                             \
      float p0 = acc0[r]; h0r[r] = __builtin_fmaxf(p0, 0.01f * p0);           \
      float p1 = acc1[r]; h1r[r] = __builtin_fmaxf(p1, 0.01f * p1);           \
    }                                                                         \
    ((short8*)(&ldsf[(P) ^ 1][0][0][0]))[wave * 64 + lane] = pack2(h0r, h1r); \
    __syncthreads();                                                          \
  }

__global__ __launch_bounds__(512)
void rnn_fused(const float* __restrict__ data,   // [T][B][I]
               const float* __restrict__ hier,   // [B][N]
               const float* __restrict__ h0,     // [B][N]
               const float* __restrict__ W_in,   // [N][I]
               const float* __restrict__ b_in,   // [N]
               const float* __restrict__ W_hh,   // [N][N]
               const float* __restrict__ b_hh,   // [N]
               const float* __restrict__ W_ff,   // [N][N]
               const float* __restrict__ b_ff,   // [N]
               const float* __restrict__ W_fc,   // [2][N]
               const float* __restrict__ b_fc,   // [2]
               float* __restrict__ out)          // [B][2]
{
  // frag store: [parity][k-slot 0..7][64 lanes][8 bf16] = 16 KiB
  __shared__ short ldsf[2][8][64][8];
  __shared__ float ldsh[16][264];  // final h scratch (padded)

  const int tid  = threadIdx.x;
  const int wave = tid >> 6;    // 0..7; owns out-neuron rows [32w, 32w+32)
  const int lane = tid & 63;
  const int g    = lane >> 4;   // k-group 0..3
  const int c    = lane & 15;   // batch col (B/C roles) or M-row (A role)
  const int b0   = blockIdx.x * 16;

  const int m0 = 32 * wave + c;   // A-tile row, mt0
  const int m1 = m0 + 16;         // mt1

  // ---- prologue: cst = 0.5*(b_hh + b_in + b_ff + hier @ W_ff^T) via MFMA ----
  f32x4 cst0 = {0.f, 0.f, 0.f, 0.f}, cst1 = {0.f, 0.f, 0.f, 0.f};
  {
    const float* hp = hier + (size_t)(b0 + c) * NDIM + 4 * g;
    const float* w0 = W_ff + (size_t)m0 * NDIM + 4 * g;
    const float* w1 = W_ff + (size_t)m1 * NDIM + 4 * g;
#pragma unroll
    for (int kt = 0; kt < 8; ++kt) {
      short8 bh  = pack2(*(const f32x4*)(hp + kt * 32), *(const f32x4*)(hp + kt * 32 + 16));
      short8 af0 = pack2(*(const f32x4*)(w0 + kt * 32), *(const f32x4*)(w0 + kt * 32 + 16));
      short8 af1 = pack2(*(const f32x4*)(w1 + kt * 32), *(const f32x4*)(w1 + kt * 32 + 16));
      cst0 = MFMA(af0, bh, cst0, 0, 0, 0);
      cst1 = MFMA(af1, bh, cst1, 0, 0, 0);
    }
  }
#pragma unroll
  for (int r = 0; r < 4; ++r) {
    int n0 = 32 * wave + 4 * g + r;
    int n1 = n0 + 16;
    cst0[r] = 0.5f * (cst0[r] + b_hh[n0] + b_in[n0] + b_ff[n0]);
    cst1[r] = 0.5f * (cst1[r] + b_hh[n1] + b_in[n1] + b_ff[n1]);
  }

  // ---- A-frags: 0.5*W_hh (diag zeroed), 0.5*W_in (I=28 padded to 32) ----
  short8 A_hh0[8], A_hh1[8], A_in0, A_in1;
  {
    const float* w0 = W_hh + (size_t)m0 * NDIM + 4 * g;
    const float* w1 = W_hh + (size_t)m1 * NDIM + 4 * g;
#pragma unroll
    for (int kt = 0; kt < 8; ++kt) {
      f32x4 lo0 = *(const f32x4*)(w0 + kt * 32);
      f32x4 hi0 = *(const f32x4*)(w0 + kt * 32 + 16);
      f32x4 lo1 = *(const f32x4*)(w1 + kt * 32);
      f32x4 hi1 = *(const f32x4*)(w1 + kt * 32 + 16);
#pragma unroll
      for (int j = 0; j < 4; ++j) {
        int kl = kt * 32 + 4 * g + j, kh = kl + 16;
        lo0[j] = (kl == m0) ? 0.f : 0.5f * lo0[j];
        hi0[j] = (kh == m0) ? 0.f : 0.5f * hi0[j];
        lo1[j] = (kl == m1) ? 0.f : 0.5f * lo1[j];
        hi1[j] = (kh == m1) ? 0.f : 0.5f * hi1[j];
      }
      A_hh0[kt] = pack2(lo0, hi0);
      A_hh1[kt] = pack2(lo1, hi1);
    }
    const float* p0 = W_in + (size_t)m0 * IDIM;
    const float* p1 = W_in + (size_t)m1 * IDIM;
    f32x4 lo0 = *(const f32x4*)(p0 + 4 * g);
    f32x4 lo1 = *(const f32x4*)(p1 + 4 * g);
    f32x4 hi0 = {0.f, 0.f, 0.f, 0.f}, hi1 = {0.f, 0.f, 0.f, 0.f};
    if (g < 3) {
      hi0 = *(const f32x4*)(p0 + 16 + 4 * g);
      hi1 = *(const f32x4*)(p1 + 16 + 4 * g);
    }
#pragma unroll
    for (int j = 0; j < 4; ++j) {
      lo0[j] *= 0.5f; hi0[j] *= 0.5f; lo1[j] *= 0.5f; hi1[j] *= 0.5f;
    }
    A_in0 = pack2(lo0, hi0);
    A_in1 = pack2(lo1, hi1);
  }

  // ---- h0: f32 state in C-layout + initial bf16 frag into buf 0 ----
  f32x4 h0r, h1r;
  {
    const float* hp = h0 + (size_t)(b0 + c) * NDIM + 32 * wave + 4 * g;
    h0r = *(const f32x4*)hp;
    h1r = *(const f32x4*)(hp + 16);
    ((short8*)(&ldsf[0][0][0][0]))[wave * 64 + lane] = pack2(h0r, h1r);
  }

  // ---- data register prefetch for t=0,1 ----
  const float* dptr = data + (size_t)(b0 + c) * IDIM + 4 * g;
  f32x4 dlo0, dlo1;
  f32x4 dhi0 = {0.f, 0.f, 0.f, 0.f}, dhi1 = {0.f, 0.f, 0.f, 0.f};
  dlo0 = *(const f32x4*)dptr;
  dlo1 = *(const f32x4*)(dptr + (size_t)BATCH * IDIM);
  if (g < 3) {
    dhi0 = *(const f32x4*)(dptr + 16);
    dhi1 = *(const f32x4*)(dptr + (size_t)BATCH * IDIM + 16);
  }

  __syncthreads();

  // ---- time loop, unrolled x2 for compile-time parities / named reg sets ----
  for (int t = 0; t < TSTEPS; t += 2) {
    RNN_STEP(0, dlo0, dhi0, t)
    RNN_STEP(1, dlo1, dhi1, t + 1)
  }

  // ---- readout: out = hT @ W_fc^T + b_fc ----
  *(f32x4*)(&ldsh[c][32 * wave + 4 * g])      = h0r;
  *(f32x4*)(&ldsh[c][32 * wave + 16 + 4 * g]) = h1r;
  __syncthreads();
  if (tid < 32) {
    int b = tid >> 1, cls = tid & 1;
    float s = b_fc[cls];
    const float* wf = W_fc + (size_t)cls * NDIM;
#pragma unroll 8
    for (int n = 0; n < NDIM; ++n) s += ldsh[b][n] * wf[n];
    out[(size_t)(b0 + b) * 2 + cls] = s;
  }
}

extern "C" void kernel_launch(void* const* d_in, const int* in_sizes, int n_in,
                              void* d_out, int out_size, void* d_ws, size_t ws_size,
                              hipStream_t stream) {
  const float* data = (const float*)d_in[0];
  const float* hier = (const float*)d_in[1];
  const float* h0   = (const float*)d_in[2];
  const float* W_in = (const float*)d_in[3];
  const float* b_in = (const float*)d_in[4];
  const float* W_hh = (const float*)d_in[5];
  const float* b_hh = (const float*)d_in[6];
  const float* W_ff = (const float*)d_in[7];
  const float* b_ff = (const float*)d_in[8];
  const float* W_fc = (const float*)d_in[9];
  const float* b_fc = (const float*)d_in[10];
  rnn_fused<<<dim3(BATCH / 16), dim3(512), 0, stream>>>(
      data, hier, h0, W_in, b_in, W_hh, b_hh, W_ff, b_ff, W_fc, b_fc,
      (float*)d_out);
}

// Round 2
// 1020.512 us; speedup vs baseline: 1.0386x; 1.0386x over previous
//
#include <hip/hip_runtime.h>
#include <stdint.h>
#include <stddef.h>

#define TSTEPS 2048
#define BATCH  512
#define IDIM   28
#define NDIM   256

typedef __attribute__((ext_vector_type(4))) float f32x4;
typedef __attribute__((ext_vector_type(8))) short short8;

#define MFMA __builtin_amdgcn_mfma_f32_16x16x32_bf16

// pack two f32x4 into 8 bf16 (RNE) slots: v[0..3]=a, v[4..7]=b
__device__ __forceinline__ short8 pack2(f32x4 a, f32x4 b) {
  union { uint32_t u[4]; short8 s; } r;
  asm("v_cvt_pk_bf16_f32 %0, %1, %2" : "=v"(r.u[0]) : "v"(a[0]), "v"(a[1]));
  asm("v_cvt_pk_bf16_f32 %0, %1, %2" : "=v"(r.u[1]) : "v"(a[2]), "v"(a[3]));
  asm("v_cvt_pk_bf16_f32 %0, %1, %2" : "=v"(r.u[2]) : "v"(b[0]), "v"(b[1]));
  asm("v_cvt_pk_bf16_f32 %0, %1, %2" : "=v"(r.u[3]) : "v"(b[2]), "v"(b[3]));
  return r.s;
}

// Barrier that does NOT drain vmcnt: LDS-write completion only, then raw
// s_barrier. In-flight global prefetch loads stay outstanding across it
// (T4 / m218 pattern); the compiler inserts counted vmcnt before first use.
#define LDS_BARRIER()                                       \
  do {                                                      \
    __asm__ volatile("s_waitcnt lgkmcnt(0)" ::: "memory");  \
    __builtin_amdgcn_s_barrier();                           \
    __asm__ volatile("" ::: "memory");                      \
  } while (0)

// One timestep. P = LDS buffer parity (== t&1). DLO/DHI hold data[t] (f32),
// and get re-loaded with data[t+4] (distance-4 register prefetch).
#define RNN_STEP(P, DLO, DHI, tcur)                                           \
  {                                                                           \
    short8 Bx = pack2(DLO, DHI);                                              \
    {                                                                         \
      int tt = (tcur) + 4; tt = (tt > TSTEPS - 1) ? (TSTEPS - 1) : tt;        \
      const float* rp = dptr + (size_t)tt * (BATCH * IDIM);                   \
      DLO = *(const f32x4*)rp;                                                \
      if (g < 3) DHI = *(const f32x4*)(rp + 16);                              \
    }                                                                         \
    const short8* rb = (const short8*)(&ldsf[(P)][0][0][0]);                  \
    short8 B0 = rb[0 * 64 + lane], B4 = rb[4 * 64 + lane];                    \
    short8 B1 = rb[1 * 64 + lane], B5 = rb[5 * 64 + lane];                    \
    short8 B2 = rb[2 * 64 + lane], B6 = rb[6 * 64 + lane];                    \
    short8 B3 = rb[3 * 64 + lane], B7 = rb[7 * 64 + lane];                    \
    f32x4 acc0a, acc1a;                                                       \
    f32x4 acc0b = {0.f, 0.f, 0.f, 0.f}, acc1b = {0.f, 0.f, 0.f, 0.f};        \
    _Pragma("unroll")                                                         \
    for (int r = 0; r < 4; ++r) {                                             \
      acc0a[r] = __builtin_fmaf(0.5f, h0r[r], cst0[r]);                       \
      acc1a[r] = __builtin_fmaf(0.5f, h1r[r], cst1[r]);                       \
    }                                                                         \
    /* 4 independent chains of depth 5 (a: kt0-3, b: kt4-7 + input) */        \
    acc0a = MFMA(A_hh0[0], B0, acc0a, 0, 0, 0);                               \
    acc1a = MFMA(A_hh1[0], B0, acc1a, 0, 0, 0);                               \
    acc0b = MFMA(A_hh0[4], B4, acc0b, 0, 0, 0);                               \
    acc1b = MFMA(A_hh1[4], B4, acc1b, 0, 0, 0);                               \
    acc0a = MFMA(A_hh0[1], B1, acc0a, 0, 0, 0);                               \
    acc1a = MFMA(A_hh1[1], B1, acc1a, 0, 0, 0);                               \
    acc0b = MFMA(A_hh0[5], B5, acc0b, 0, 0, 0);                               \
    acc1b = MFMA(A_hh1[5], B5, acc1b, 0, 0, 0);                               \
    acc0a = MFMA(A_hh0[2], B2, acc0a, 0, 0, 0);                               \
    acc1a = MFMA(A_hh1[2], B2, acc1a, 0, 0, 0);                               \
    acc0b = MFMA(A_hh0[6], B6, acc0b, 0, 0, 0);                               \
    acc1b = MFMA(A_hh1[6], B6, acc1b, 0, 0, 0);                               \
    acc0a = MFMA(A_hh0[3], B3, acc0a, 0, 0, 0);                               \
    acc1a = MFMA(A_hh1[3], B3, acc1a, 0, 0, 0);                               \
    acc0b = MFMA(A_hh0[7], B7, acc0b, 0, 0, 0);                               \
    acc1b = MFMA(A_hh1[7], B7, acc1b, 0, 0, 0);                               \
    acc0b = MFMA(A_in0, Bx, acc0b, 0, 0, 0);                                  \
    acc1b = MFMA(A_in1, Bx, acc1b, 0, 0, 0);                                  \
    _Pragma("unroll")                                                         \
    for (int r = 0; r < 4; ++r) {                                             \
      float p0 = acc0a[r] + acc0b[r]; h0r[r] = __builtin_fmaxf(p0, 0.01f * p0); \
      float p1 = acc1a[r] + acc1b[r]; h1r[r] = __builtin_fmaxf(p1, 0.01f * p1); \
    }                                                                         \
    ((short8*)(&ldsf[(P) ^ 1][0][0][0]))[wave * 64 + lane] = pack2(h0r, h1r); \
    LDS_BARRIER();                                                            \
  }

__global__ __launch_bounds__(512)
void rnn_fused(const float* __restrict__ data,   // [T][B][I]
               const float* __restrict__ hier,   // [B][N]
               const float* __restrict__ h0,     // [B][N]
               const float* __restrict__ W_in,   // [N][I]
               const float* __restrict__ b_in,   // [N]
               const float* __restrict__ W_hh,   // [N][N]
               const float* __restrict__ b_hh,   // [N]
               const float* __restrict__ W_ff,   // [N][N]
               const float* __restrict__ b_ff,   // [N]
               const float* __restrict__ W_fc,   // [2][N]
               const float* __restrict__ b_fc,   // [2]
               float* __restrict__ out)          // [B][2]
{
  // frag store: [parity][k-slot 0..7][64 lanes][8 bf16] = 16 KiB
  __shared__ short ldsf[2][8][64][8];
  __shared__ float ldsh[16][264];  // final h scratch (padded)

  const int tid  = threadIdx.x;
  const int wave = tid >> 6;    // 0..7; owns out-neuron rows [32w, 32w+32)
  const int lane = tid & 63;
  const int g    = lane >> 4;   // k-group 0..3
  const int c    = lane & 15;   // batch col (B/C roles) or M-row (A role)
  const int b0   = blockIdx.x * 16;

  const int m0 = 32 * wave + c;   // A-tile row, mt0
  const int m1 = m0 + 16;         // mt1

  // ---- prologue: cst = 0.5*(b_hh + b_in + b_ff + hier @ W_ff^T) via MFMA ----
  f32x4 cst0 = {0.f, 0.f, 0.f, 0.f}, cst1 = {0.f, 0.f, 0.f, 0.f};
  {
    const float* hp = hier + (size_t)(b0 + c) * NDIM + 4 * g;
    const float* w0 = W_ff + (size_t)m0 * NDIM + 4 * g;
    const float* w1 = W_ff + (size_t)m1 * NDIM + 4 * g;
#pragma unroll
    for (int kt = 0; kt < 8; ++kt) {
      short8 bh  = pack2(*(const f32x4*)(hp + kt * 32), *(const f32x4*)(hp + kt * 32 + 16));
      short8 af0 = pack2(*(const f32x4*)(w0 + kt * 32), *(const f32x4*)(w0 + kt * 32 + 16));
      short8 af1 = pack2(*(const f32x4*)(w1 + kt * 32), *(const f32x4*)(w1 + kt * 32 + 16));
      cst0 = MFMA(af0, bh, cst0, 0, 0, 0);
      cst1 = MFMA(af1, bh, cst1, 0, 0, 0);
    }
  }
#pragma unroll
  for (int r = 0; r < 4; ++r) {
    int n0 = 32 * wave + 4 * g + r;
    int n1 = n0 + 16;
    cst0[r] = 0.5f * (cst0[r] + b_hh[n0] + b_in[n0] + b_ff[n0]);
    cst1[r] = 0.5f * (cst1[r] + b_hh[n1] + b_in[n1] + b_ff[n1]);
  }

  // ---- A-frags: 0.5*W_hh (diag zeroed), 0.5*W_in (I=28 padded to 32) ----
  short8 A_hh0[8], A_hh1[8], A_in0, A_in1;
  {
    const float* w0 = W_hh + (size_t)m0 * NDIM + 4 * g;
    const float* w1 = W_hh + (size_t)m1 * NDIM + 4 * g;
#pragma unroll
    for (int kt = 0; kt < 8; ++kt) {
      f32x4 lo0 = *(const f32x4*)(w0 + kt * 32);
      f32x4 hi0 = *(const f32x4*)(w0 + kt * 32 + 16);
      f32x4 lo1 = *(const f32x4*)(w1 + kt * 32);
      f32x4 hi1 = *(const f32x4*)(w1 + kt * 32 + 16);
#pragma unroll
      for (int j = 0; j < 4; ++j) {
        int kl = kt * 32 + 4 * g + j, kh = kl + 16;
        lo0[j] = (kl == m0) ? 0.f : 0.5f * lo0[j];
        hi0[j] = (kh == m0) ? 0.f : 0.5f * hi0[j];
        lo1[j] = (kl == m1) ? 0.f : 0.5f * lo1[j];
        hi1[j] = (kh == m1) ? 0.f : 0.5f * hi1[j];
      }
      A_hh0[kt] = pack2(lo0, hi0);
      A_hh1[kt] = pack2(lo1, hi1);
    }
    const float* p0 = W_in + (size_t)m0 * IDIM;
    const float* p1 = W_in + (size_t)m1 * IDIM;
    f32x4 lo0 = *(const f32x4*)(p0 + 4 * g);
    f32x4 lo1 = *(const f32x4*)(p1 + 4 * g);
    f32x4 hi0 = {0.f, 0.f, 0.f, 0.f}, hi1 = {0.f, 0.f, 0.f, 0.f};
    if (g < 3) {
      hi0 = *(const f32x4*)(p0 + 16 + 4 * g);
      hi1 = *(const f32x4*)(p1 + 16 + 4 * g);
    }
#pragma unroll
    for (int j = 0; j < 4; ++j) {
      lo0[j] *= 0.5f; hi0[j] *= 0.5f; lo1[j] *= 0.5f; hi1[j] *= 0.5f;
    }
    A_in0 = pack2(lo0, hi0);
    A_in1 = pack2(lo1, hi1);
  }

  // ---- h0: f32 state in C-layout + initial bf16 frag into buf 0 ----
  f32x4 h0r, h1r;
  {
    const float* hp = h0 + (size_t)(b0 + c) * NDIM + 32 * wave + 4 * g;
    h0r = *(const f32x4*)hp;
    h1r = *(const f32x4*)(hp + 16);
    ((short8*)(&ldsf[0][0][0][0]))[wave * 64 + lane] = pack2(h0r, h1r);
  }

  // ---- data register prefetch for t=0..3 (distance-4 pipeline) ----
  const float* dptr = data + (size_t)(b0 + c) * IDIM + 4 * g;
  f32x4 dlo0, dlo1, dlo2, dlo3;
  f32x4 dhi0 = {0.f, 0.f, 0.f, 0.f}, dhi1 = {0.f, 0.f, 0.f, 0.f};
  f32x4 dhi2 = {0.f, 0.f, 0.f, 0.f}, dhi3 = {0.f, 0.f, 0.f, 0.f};
  dlo0 = *(const f32x4*)dptr;
  dlo1 = *(const f32x4*)(dptr + (size_t)1 * BATCH * IDIM);
  dlo2 = *(const f32x4*)(dptr + (size_t)2 * BATCH * IDIM);
  dlo3 = *(const f32x4*)(dptr + (size_t)3 * BATCH * IDIM);
  if (g < 3) {
    dhi0 = *(const f32x4*)(dptr + 16);
    dhi1 = *(const f32x4*)(dptr + (size_t)1 * BATCH * IDIM + 16);
    dhi2 = *(const f32x4*)(dptr + (size_t)2 * BATCH * IDIM + 16);
    dhi3 = *(const f32x4*)(dptr + (size_t)3 * BATCH * IDIM + 16);
  }

  __syncthreads();  // one-time full barrier (initial frag + prefetch drain ok)

  // ---- time loop, unrolled x4: compile-time parities + 4 prefetch slots ----
  for (int t = 0; t < TSTEPS; t += 4) {
    RNN_STEP(0, dlo0, dhi0, t)
    RNN_STEP(1, dlo1, dhi1, t + 1)
    RNN_STEP(0, dlo2, dhi2, t + 2)
    RNN_STEP(1, dlo3, dhi3, t + 3)
  }

  // ---- readout: out = hT @ W_fc^T + b_fc ----
  *(f32x4*)(&ldsh[c][32 * wave + 4 * g])      = h0r;
  *(f32x4*)(&ldsh[c][32 * wave + 16 + 4 * g]) = h1r;
  __syncthreads();
  if (tid < 32) {
    int b = tid >> 1, cls = tid & 1;
    float s = b_fc[cls];
    const float* wf = W_fc + (size_t)cls * NDIM;
#pragma unroll 8
    for (int n = 0; n < NDIM; ++n) s += ldsh[b][n] * wf[n];
    out[(size_t)(b0 + b) * 2 + cls] = s;
  }
}

extern "C" void kernel_launch(void* const* d_in, const int* in_sizes, int n_in,
                              void* d_out, int out_size, void* d_ws, size_t ws_size,
                              hipStream_t stream) {
  const float* data = (const float*)d_in[0];
  const float* hier = (const float*)d_in[1];
  const float* h0   = (const float*)d_in[2];
  const float* W_in = (const float*)d_in[3];
  const float* b_in = (const float*)d_in[4];
  const float* W_hh = (const float*)d_in[5];
  const float* b_hh = (const float*)d_in[6];
  const float* W_ff = (const float*)d_in[7];
  const float* b_ff = (const float*)d_in[8];
  const float* W_fc = (const float*)d_in[9];
  const float* b_fc = (const float*)d_in[10];
  rnn_fused<<<dim3(BATCH / 16), dim3(512), 0, stream>>>(
      data, hier, h0, W_in, b_in, W_hh, b_hh, W_ff, b_ff, W_fc, b_fc,
      (float*)d_out);
}